// Round 6
// baseline (296.550 us; speedup 1.0000x reference)
//
#include <hip/hip_runtime.h>
#include <hip/hip_bf16.h>

// Native vector type for nontemporal builtins.
typedef float vf4 __attribute__((ext_vector_type(4)));

// Phase 0: init last_idx to -1.
__global__ void k_init_last(int4* __restrict__ last_idx4, int n4) {
    int stride = gridDim.x * blockDim.x;
    for (int i = blockIdx.x * blockDim.x + threadIdx.x; i < n4; i += stride) {
        last_idx4[i] = make_int4(-1, -1, -1, -1);
    }
}

// Phase 1: per-node last event index via atomicMax.
__global__ void k_last_idx(const int* __restrict__ node_ids,
                           int* __restrict__ last_idx, int E) {
    int i = blockIdx.x * blockDim.x + threadIdx.x;
    if (i < E) {
        atomicMax(&last_idx[node_ids[i]], i);
    }
}

// Phase 2 (fused gather): 4 threads per node, 8x16B each -> 8 outstanding
// nontemporal loads per thread. Lanes q=0..3 read 64B contiguous per step;
// the 8 steps cover the whole 512B row. NT on single-touch msg/out streams;
// times/last_idx stay cached.
__global__ void k_gather(const vf4* __restrict__ msg,
                         const int* __restrict__ last_idx,
                         const float* __restrict__ times,
                         vf4* __restrict__ out_msg,
                         float* __restrict__ out_valid,
                         float* __restrict__ out_times, int N) {
    int t = blockIdx.x * blockDim.x + threadIdx.x;
    int node = t >> 2;
    int q = t & 3;
    if (node >= N) return;
    int li = last_idx[node];
    size_t ob = (size_t)node * 32 + q;
    if (li >= 0) {
        size_t ib = (size_t)li * 32 + q;
        vf4 v0 = __builtin_nontemporal_load(&msg[ib]);
        vf4 v1 = __builtin_nontemporal_load(&msg[ib + 4]);
        vf4 v2 = __builtin_nontemporal_load(&msg[ib + 8]);
        vf4 v3 = __builtin_nontemporal_load(&msg[ib + 12]);
        vf4 v4 = __builtin_nontemporal_load(&msg[ib + 16]);
        vf4 v5 = __builtin_nontemporal_load(&msg[ib + 20]);
        vf4 v6 = __builtin_nontemporal_load(&msg[ib + 24]);
        vf4 v7 = __builtin_nontemporal_load(&msg[ib + 28]);
        __builtin_nontemporal_store(v0, &out_msg[ob]);
        __builtin_nontemporal_store(v1, &out_msg[ob + 4]);
        __builtin_nontemporal_store(v2, &out_msg[ob + 8]);
        __builtin_nontemporal_store(v3, &out_msg[ob + 12]);
        __builtin_nontemporal_store(v4, &out_msg[ob + 16]);
        __builtin_nontemporal_store(v5, &out_msg[ob + 20]);
        __builtin_nontemporal_store(v6, &out_msg[ob + 24]);
        __builtin_nontemporal_store(v7, &out_msg[ob + 28]);
    } else {
        vf4 z = (vf4)0.0f;
        __builtin_nontemporal_store(z, &out_msg[ob]);
        __builtin_nontemporal_store(z, &out_msg[ob + 4]);
        __builtin_nontemporal_store(z, &out_msg[ob + 8]);
        __builtin_nontemporal_store(z, &out_msg[ob + 12]);
        __builtin_nontemporal_store(z, &out_msg[ob + 16]);
        __builtin_nontemporal_store(z, &out_msg[ob + 20]);
        __builtin_nontemporal_store(z, &out_msg[ob + 24]);
        __builtin_nontemporal_store(z, &out_msg[ob + 28]);
    }
    if (q == 0) {
        out_valid[node] = (li >= 0) ? 1.0f : 0.0f;
        out_times[node] = (li >= 0) ? times[li] : 0.0f;
    }
}

extern "C" void kernel_launch(void* const* d_in, const int* in_sizes, int n_in,
                              void* d_out, int out_size, void* d_ws, size_t ws_size,
                              hipStream_t stream) {
    const int*   node_ids = (const int*)d_in[0];
    const float* msg      = (const float*)d_in[1];
    const float* times    = (const float*)d_in[2];
    const int E = in_sizes[0];
    const int N = out_size / 130;   // out = valid[N] + msg[N*128] + times[N]

    float* out_valid = (float*)d_out;
    float* out_msg   = (float*)d_out + N;
    float* out_times = (float*)d_out + N + (size_t)N * 128;

    int* last_idx = (int*)d_ws;     // N ints (4 MB)

    const int B = 256;

    k_init_last<<<2048, B, 0, stream>>>((int4*)last_idx, N / 4);

    k_last_idx<<<(E + B - 1) / B, B, 0, stream>>>(node_ids, last_idx, E);

    long long total = (long long)N * 4;
    k_gather<<<(int)((total + B - 1) / B), B, 0, stream>>>(
        (const vf4*)msg, last_idx, times,
        (vf4*)out_msg, out_valid, out_times, N);
}

// Round 7
// 251.866 us; speedup vs baseline: 1.1774x; 1.1774x over previous
//
#include <hip/hip_runtime.h>
#include <hip/hip_bf16.h>

// Native vector type for nontemporal builtins (HIP's float4 is a class and
// is rejected by __builtin_nontemporal_load/store).
typedef float vf4 __attribute__((ext_vector_type(4)));

// Phase 0: init last_idx to -1 with a grid-stride int4 kernel.
__global__ void k_init_last(int4* __restrict__ last_idx4, int n4) {
    int stride = gridDim.x * blockDim.x;
    for (int i = blockIdx.x * blockDim.x + threadIdx.x; i < n4; i += stride) {
        last_idx4[i] = make_int4(-1, -1, -1, -1);
    }
}

// Phase 1: per-node last event index via atomicMax (1 event/thread).
__global__ void k_last_idx(const int* __restrict__ node_ids,
                           int* __restrict__ last_idx, int E) {
    int i = blockIdx.x * blockDim.x + threadIdx.x;
    if (i < E) {
        atomicMax(&last_idx[node_ids[i]], i);
    }
}

// Phase 2 (fused): gather message rows + valid flag + times.
// 8 threads per node, 4x16B each -> 4 outstanding loads per thread; each
// load instruction covers 128B contiguous across the 8-lane group.
// Nontemporal on the single-touch msg/out streams.
__global__ void k_gather(const vf4* __restrict__ msg,
                         const int* __restrict__ last_idx,
                         const float* __restrict__ times,
                         vf4* __restrict__ out_msg,
                         float* __restrict__ out_valid,
                         float* __restrict__ out_times, int N) {
    int t = blockIdx.x * blockDim.x + threadIdx.x;
    int node = t >> 3;
    int q = t & 7;
    if (node >= N) return;
    int li = last_idx[node];
    size_t obase = (size_t)node * 32 + q;
    if (li >= 0) {
        size_t ibase = (size_t)li * 32 + q;
        vf4 v0 = __builtin_nontemporal_load(&msg[ibase]);
        vf4 v1 = __builtin_nontemporal_load(&msg[ibase + 8]);
        vf4 v2 = __builtin_nontemporal_load(&msg[ibase + 16]);
        vf4 v3 = __builtin_nontemporal_load(&msg[ibase + 24]);
        __builtin_nontemporal_store(v0, &out_msg[obase]);
        __builtin_nontemporal_store(v1, &out_msg[obase + 8]);
        __builtin_nontemporal_store(v2, &out_msg[obase + 16]);
        __builtin_nontemporal_store(v3, &out_msg[obase + 24]);
    } else {
        vf4 z = (vf4)0.0f;
        __builtin_nontemporal_store(z, &out_msg[obase]);
        __builtin_nontemporal_store(z, &out_msg[obase + 8]);
        __builtin_nontemporal_store(z, &out_msg[obase + 16]);
        __builtin_nontemporal_store(z, &out_msg[obase + 24]);
    }
    if (q == 0) {
        out_valid[node] = (li >= 0) ? 1.0f : 0.0f;
        out_times[node] = (li >= 0) ? times[li] : 0.0f;
    }
}

extern "C" void kernel_launch(void* const* d_in, const int* in_sizes, int n_in,
                              void* d_out, int out_size, void* d_ws, size_t ws_size,
                              hipStream_t stream) {
    const int*   node_ids = (const int*)d_in[0];
    const float* msg      = (const float*)d_in[1];
    const float* times    = (const float*)d_in[2];
    const int E = in_sizes[0];
    const int N = out_size / 130;   // out = valid[N] + msg[N*128] + times[N]

    float* out_valid = (float*)d_out;
    float* out_msg   = (float*)d_out + N;
    float* out_times = (float*)d_out + N + (size_t)N * 128;

    int* last_idx = (int*)d_ws;     // N ints (4 MB)

    const int B = 256;

    k_init_last<<<2048, B, 0, stream>>>((int4*)last_idx, N / 4);

    k_last_idx<<<(E + B - 1) / B, B, 0, stream>>>(node_ids, last_idx, E);

    long long total = (long long)N * 8;
    k_gather<<<(int)((total + B - 1) / B), B, 0, stream>>>(
        (const vf4*)msg, last_idx, times,
        (vf4*)out_msg, out_valid, out_times, N);
}